// Round 15
// baseline (353.706 us; speedup 1.0000x reference)
//
#include <hip/hip_runtime.h>

namespace {

typedef __attribute__((ext_vector_type(8))) short short8;   // MFMA A/B frag (8 bf16)
typedef __attribute__((ext_vector_type(4))) float floatx4;  // MFMA C/D frag

constexpr int T     = 512;
constexpr int H     = 64;
constexpr int TPB   = 1024;  // 16 waves = 4/SIMD, one barrier domain, ZERO duplication
constexpr int MB    = 8;     // grid 256 -> 1 block/CU, all CUs
constexpr int HST   = 72;    // ushorts per (bat,type) h-row: 64 data + 8 pad
constexpr int HROWS = 16;    // 2*MB rows (R14 BUG: was sized 8 rows -> OOB corruption)
constexpr int XSTR  = 516;   // xs row stride (floats)
constexpr int FSTR  = 68;    // hf32 row stride (floats, head only)

constexpr int DPP_ROR8 = 0x128;  // row_ror:8 -> lane i reads lane i^8 (within row of 16)

__device__ __forceinline__ ushort f2bf(float x) {  // fp32 -> bf16 RN-even (finite)
  unsigned u = __float_as_uint(x);
  unsigned r = u + 0x7fffu + ((u >> 16) & 1u);
  return (ushort)(r >> 16);
}
__device__ __forceinline__ float bf2f(ushort h) {
  return __uint_as_float(((unsigned)h) << 16);
}
__device__ __forceinline__ float fsig(float x) {
  return __builtin_amdgcn_rcpf(1.0f + __expf(-x));
}
__device__ __forceinline__ float ftanh(float x) {
  return fmaf(-2.0f, __builtin_amdgcn_rcpf(1.0f + __expf(2.0f * x)), 1.0f);
}
__device__ __forceinline__ float swz8(float v) {   // value from lane^8 (row of 16), VALU pipe
  return __int_as_float(__builtin_amdgcn_update_dpp(
      0, __float_as_int(v), DPP_ROR8, 0xf, 0xf, true));
}

// R15 = R14 with the h-buffer sized correctly (16 (bat,type) rows, not 8).
//   16 waves x 1 tile (4 waves/SIMD, no duplication).
//   B cols (verified R9): 0-7 = h_hi(batch 0-7), 8-15 = h_lo(batch 0-7).
//   A-row permutation (verified R12): A row m of tile wj loads W_hh row
//   64*(m&3) + 4*wj + (m>>2)  =>  D reg j of lane (n,kg) = gate j of unit
//   4*wj+kg, batch n&7 (duplicated over nhi=n>>3).
//   Per wave per step: 4 MFMA (hi/lo x 2 K-halves), 2 ds_read_b128,
//   p[j] = s + swz8(s) + pinit (symmetric hi/lo col merge — identical on the
//   dup pair, so the pair splits the h hi/lo writes: 1 ds_write per lane).
//   One barrier/step; h double-buffered.
__global__ __launch_bounds__(TPB, 1)
void lstm_mfma(const float* __restrict__ xg,
               const float* __restrict__ W_ih,
               const float* __restrict__ W_hh,
               const float* __restrict__ b_ih,
               const float* __restrict__ b_hh,
               const float* __restrict__ fc1_w,
               const float* __restrict__ fc1_b,
               const float* __restrict__ fc2_w,
               const float* __restrict__ fc2_b,
               float* __restrict__ out)
{
  __shared__ __align__(16) ushort hA[HROWS * HST];  // h double-buffer
  __shared__ __align__(16) ushort hB[HROWS * HST];
  __shared__ __align__(16) float  xs[MB * XSTR];
  __shared__ __align__(16) float  hf[MB * FSTR];    // final h fp32 (head; written once)
  __shared__ float zs[MB][16];

  const int tid  = threadIdx.x;
  const int b0   = blockIdx.x * MB;
  const int lane = tid & 63;
  const int wj   = tid >> 6;       // wave 0..15 -> tile wj (units 4wj..4wj+3)
  const int n    = lane & 15;      // MFMA col: batch n&7, type n>>3 (0=hi,1=lo)
  const int kg   = lane >> 4;      // k-group (A/B), row-quad (D)
  const int bat  = n & 7;
  const int nhi  = n >> 3;

  // ---- stage x (coalesced float4; exactly 1 iter/thread) ----
  for (int i = tid; i < MB * T / 4; i += TPB) {
    const int xb = i >> 7, tq = i & 127;
    float4 v = ((const float4*)(xg + (size_t)(b0 + xb) * T))[tq];
    *(float4*)&xs[xb * XSTR + tq * 4] = v;
  }
  // ---- zero h buffers (h0 = 0; pads stay 0) ----
  for (int i = tid; i < HROWS * HST; i += TPB) { hA[i] = 0; hB[i] = 0; }

  // ---- A-frags for tile wj (gate-interleaved row permutation, verified R12) ----
  short8 whi[2], wlo[2];           // [k-half]
  {
    const int arow = 64 * (n & 3) + 4 * wj + (n >> 2);  // gate n&3, local unit n>>2
    const float* wr = W_hh + arow * H + 8 * kg;
    const float4 p0 = *(const float4*)(wr + 0);
    const float4 p1 = *(const float4*)(wr + 4);
    const float4 p2 = *(const float4*)(wr + 32);
    const float4 p3 = *(const float4*)(wr + 36);
    const float v0[8] = {p0.x, p0.y, p0.z, p0.w, p1.x, p1.y, p1.z, p1.w};
    const float v1[8] = {p2.x, p2.y, p2.z, p2.w, p3.x, p3.y, p3.z, p3.w};
#pragma unroll
    for (int j = 0; j < 8; ++j) {
      const ushort h0 = f2bf(v0[j]);
      whi[0][j] = (short)h0;
      wlo[0][j] = (short)f2bf(v0[j] - bf2f(h0));   // exact remainder, then RN
      const ushort h1 = f2bf(v1[j]);
      whi[1][j] = (short)h1;
      wlo[1][j] = (short)f2bf(v1[j] - bf2f(h1));
    }
  }

  // ---- owned c-state: unit u = 4wj + kg, batch bat (dup over nhi) ----
  const int u = 4 * wj + kg;
  float bia[4], wih[4];
#pragma unroll
  for (int j = 0; j < 4; ++j) {                 // gate rows: i,f,g,o = 64j + u
    const int row = 64 * j + u;
    bia[j] = b_ih[row] + b_hh[row];
    wih[j] = W_ih[row];
  }

  const int rdoff = (2 * bat + nhi) * HST + 8 * kg;  // my col's (bat,type) row
  const int woff  = (2 * bat + nhi) * HST + u;       // my h write (hi or lo by nhi)
  const float* xq = &xs[bat * XSTR];
  float c = 0.0f, hk = 0.0f;

  __syncthreads();

#define STEP(HR, HW, TT)                                                       \
  {                                                                            \
    const ushort* hb = (HR) + rdoff;                                           \
    const short8 f0 = *(const short8*)(hb + 0);    /* k 8kg..8kg+8   (my type) */ \
    const short8 f1 = *(const short8*)(hb + 32);   /* k 32+8kg..+8 */          \
    const floatx4 zf = {0.f, 0.f, 0.f, 0.f};                                   \
    floatx4 d1 = __builtin_amdgcn_mfma_f32_16x16x32_bf16(whi[0], f0, zf, 0, 0, 0); \
    floatx4 d2 = __builtin_amdgcn_mfma_f32_16x16x32_bf16(wlo[0], f0, zf, 0, 0, 0); \
    d1 = __builtin_amdgcn_mfma_f32_16x16x32_bf16(whi[1], f1, d1, 0, 0, 0);     \
    d2 = __builtin_amdgcn_mfma_f32_16x16x32_bf16(wlo[1], f1, d2, 0, 0, 0);     \
    const float xt = xq[(TT)];                                                 \
    float p[4];                                                                \
    _Pragma("unroll") for (int j = 0; j < 4; ++j) {                            \
      const float s = d1[j] + d2[j];                                           \
      p[j] = s + swz8(s) + fmaf(xt, wih[j], bia[j]);                           \
    }                                                                          \
    const float ig = fsig(p[0]);                                               \
    const float fg = fsig(p[1]);                                               \
    const float gc = ftanh(p[2]);                                              \
    const float og = fsig(p[3]);                                               \
    c  = fmaf(fg, c, ig * gc);                                                 \
    hk = og * ftanh(c);                                                        \
    const ushort hib = (ushort)(__float_as_uint(hk) >> 16);  /* trunc split */ \
    (HW)[woff] = nhi ? f2bf(hk - bf2f(hib)) : hib;                             \
    __syncthreads();                                                           \
  }

  for (int t = 0; t < T; t += 2) {
    STEP(hA, hB, t);
    STEP(hB, hA, t + 1);
  }
#undef STEP

  // ---- final h (fp32, from registers) -> LDS once; then the head ----
  if (nhi == 0) hf[bat * FSTR + u] = hk;
  __syncthreads();
  if (tid < MB * 16) {
    const int bq = tid >> 4, j2 = tid & 15;   // 8 batches x 16 hidden2
    float s = fc1_b[j2];
    const float* fw = fc1_w + j2 * H;
#pragma unroll
    for (int k = 0; k < H; ++k) s = fmaf(hf[bq * FSTR + k], fw[k], s);
    s = fmaxf(s, 0.0f);
    zs[bq][j2] = s * fc2_w[j2];
  }
  __syncthreads();
  if (tid < MB) {
    float s = fc2_b[0];
#pragma unroll
    for (int j = 0; j < 16; ++j) s += zs[tid][j];
    out[b0 + tid] = s;
  }
}

}  // namespace

extern "C" void kernel_launch(void* const* d_in, const int* in_sizes, int n_in,
                              void* d_out, int out_size, void* d_ws, size_t ws_size,
                              hipStream_t stream) {
  const float* xg    = (const float*)d_in[0];
  const float* W_ih  = (const float*)d_in[1];
  const float* W_hh  = (const float*)d_in[2];
  const float* b_ih  = (const float*)d_in[3];
  const float* b_hh  = (const float*)d_in[4];
  const float* fc1_w = (const float*)d_in[5];
  const float* fc1_b = (const float*)d_in[6];
  const float* fc2_w = (const float*)d_in[7];
  const float* fc2_b = (const float*)d_in[8];
  float* out = (float*)d_out;

  dim3 grid(2048 / MB);   // 256 blocks -> 1 per CU, 16 waves = 4/SIMD
  dim3 block(TPB);
  hipLaunchKernelGGL(lstm_mfma, grid, block, 0, stream,
                     xg, W_ih, W_hh, b_ih, b_hh, fc1_w, fc1_b, fc2_w, fc2_b, out);
}

// Round 16
// 272.651 us; speedup vs baseline: 1.2973x; 1.2973x over previous
//
#include <hip/hip_runtime.h>

namespace {

typedef __attribute__((ext_vector_type(8))) short short8;   // MFMA A/B frag (8 bf16)
typedef __attribute__((ext_vector_type(4))) float floatx4;  // MFMA C/D frag

constexpr int T    = 512;
constexpr int H    = 64;
constexpr int TPB  = 512;   // 8 waves = 2/SIMD (R12 topology: the bracketed optimum)
constexpr int MB   = 8;     // grid 256 -> 1 block/CU, all CUs
constexpr int HST  = 152;   // ushorts per bat row: hi[0,64) pad lo[72,136) pad to 152.
                            //   76 dwords/row -> bases 12b%32 hit all 8 bank-quads;
                            //   reads quad (3b+t+kg)%8 = 2 lanes/bank (free, m136);
                            //   b16 writes 2 lanes/dword (free).
constexpr int LOFF = 72;    // lo offset (144B -> 16B-aligned b128 reads)
constexpr int XSTR = 516;   // xs row stride (floats)
constexpr int FSTR = 68;    // hf32 row stride (floats, head only)

constexpr int DPP_ROR8 = 0x128;  // row_ror:8 -> lane i reads lane i^8 (within row of 16)

__device__ __forceinline__ ushort f2bf(float x) {  // fp32 -> bf16 RN-even (finite)
  unsigned u = __float_as_uint(x);
  unsigned r = u + 0x7fffu + ((u >> 16) & 1u);
  return (ushort)(r >> 16);
}
__device__ __forceinline__ float bf2f(ushort h) {
  return __uint_as_float(((unsigned)h) << 16);
}
__device__ __forceinline__ float fsig(float x) {
  return __builtin_amdgcn_rcpf(1.0f + __expf(-x));
}
__device__ __forceinline__ float ftanh(float x) {
  return fmaf(-2.0f, __builtin_amdgcn_rcpf(1.0f + __expf(2.0f * x)), 1.0f);
}
__device__ __forceinline__ float swz8(float v) {   // value from lane^8 (row of 16), VALU pipe
  return __int_as_float(__builtin_amdgcn_update_dpp(
      0, __float_as_int(v), DPP_ROR8, 0xf, 0xf, true));
}

// R16 = R12 (262 us, verified) + diet:
//   (1) 4-term MFMA per tile fused into ONE 4-deep chain (C-accumulate):
//       d = Whi[k0]*f0 + Wlo[k0]*f0 + Whi[k1]*f1 + Wlo[k1]*f1 — at hi-cols this
//       is (Whi+Wlo)*hhi, at lo-cols (Whi+Wlo)*hlo; the tiny Wlo*hlo 4th-order
//       term matches R12's math exactly. Saves 8 v_add/wave/step.
//   (2) conflict-free strides (HST=152, lo at +72) — kills the 8.4M conflicts.
//   (3) merge: pX = dX[j] + swz8(dX[j]) (symmetric type merge, verified R9/R12),
//       p = (nhi ? pB : pA) + (bias + x*Wih).
// Topology (bracketed by R6/R10/R11/R13/R15): 8 waves x 2 tiles, 2 waves/SIMD,
// one barrier/step, h double-buffered, 16 ds_read_b128/CU/step.
// A-row permutation (verified R12): A row m of tile r loads W_hh row
// 64*(m&3)+4r+(m>>2) => D reg j of lane (n,kg) = gate j of unit 4r+kg.
// Lane owns c-state of unit 8wj+4nhi+kg, batch n&7 (dup-free trans).
__global__ __launch_bounds__(TPB, 2)
void lstm_mfma(const float* __restrict__ xg,
               const float* __restrict__ W_ih,
               const float* __restrict__ W_hh,
               const float* __restrict__ b_ih,
               const float* __restrict__ b_hh,
               const float* __restrict__ fc1_w,
               const float* __restrict__ fc1_b,
               const float* __restrict__ fc2_w,
               const float* __restrict__ fc2_b,
               float* __restrict__ out)
{
  __shared__ __align__(16) ushort hA[MB * HST];   // h double-buffer (hi | lo per bat row)
  __shared__ __align__(16) ushort hB[MB * HST];
  __shared__ __align__(16) float  xs[MB * XSTR];
  __shared__ __align__(16) float  hf[MB * FSTR];  // final h fp32 (head; written once)
  __shared__ float zs[MB][16];

  const int tid  = threadIdx.x;
  const int b0   = blockIdx.x * MB;
  const int lane = tid & 63;
  const int wj   = tid >> 6;       // wave 0..7 -> tiles {2wj, 2wj+1}
  const int n    = lane & 15;      // MFMA col: batch n&7, type n>>3 (0=hi,1=lo)
  const int kg   = lane >> 4;      // k-group (A/B), row-quad (D)
  const int bat  = n & 7;
  const int nhi  = n >> 3;

  // ---- stage x (coalesced float4) ----
  for (int i = tid; i < MB * T / 4; i += TPB) {
    const int xb = i >> 7, tq = i & 127;
    float4 v = ((const float4*)(xg + (size_t)(b0 + xb) * T))[tq];
    *(float4*)&xs[xb * XSTR + tq * 4] = v;
  }
  // ---- zero h buffers (h0 = 0; pads stay 0) ----
  for (int i = tid; i < MB * HST; i += TPB) { hA[i] = 0; hB[i] = 0; }

  // ---- A-frags for tiles 2wj, 2wj+1 (gate-interleaved permutation, verified R12) ----
  short8 whi[2][2], wlo[2][2];     // [tile][k-half]
#pragma unroll
  for (int tt = 0; tt < 2; ++tt) {
    const int r    = 2 * wj + tt;
    const int arow = 64 * (n & 3) + 4 * r + (n >> 2);   // gate n&3, local unit n>>2
    const float* wr = W_hh + arow * H + 8 * kg;
    const float4 p0 = *(const float4*)(wr + 0);
    const float4 p1 = *(const float4*)(wr + 4);
    const float4 p2 = *(const float4*)(wr + 32);
    const float4 p3 = *(const float4*)(wr + 36);
    const float v0[8] = {p0.x, p0.y, p0.z, p0.w, p1.x, p1.y, p1.z, p1.w};
    const float v1[8] = {p2.x, p2.y, p2.z, p2.w, p3.x, p3.y, p3.z, p3.w};
#pragma unroll
    for (int j = 0; j < 8; ++j) {
      const ushort h0 = f2bf(v0[j]);
      whi[tt][0][j] = (short)h0;
      wlo[tt][0][j] = (short)f2bf(v0[j] - bf2f(h0));   // exact remainder, then RN
      const ushort h1 = f2bf(v1[j]);
      whi[tt][1][j] = (short)h1;
      wlo[tt][1][j] = (short)f2bf(v1[j] - bf2f(h1));
    }
  }

  // ---- owned c-state: unit u = 8wj + 4nhi + kg, batch bat ----
  const int u = 8 * wj + 4 * nhi + kg;
  float bia[4], wih[4];
#pragma unroll
  for (int j = 0; j < 4; ++j) {                 // gate rows: i,f,g,o = 64j + u
    const int row = 64 * j + u;
    bia[j] = b_ih[row] + b_hh[row];
    wih[j] = W_ih[row];
  }

  const int rdoff = bat * HST + nhi * LOFF + 8 * kg;  // B-frag read base (ushorts)
  const int woff  = bat * HST + u;                    // h write: hi +0, lo +LOFF
  const float* xq = &xs[bat * XSTR];
  float c = 0.0f, hk = 0.0f;

  __syncthreads();

#define STEP(HR, HW, TT)                                                       \
  {                                                                            \
    const ushort* hb = (HR) + rdoff;                                           \
    const short8 f0 = *(const short8*)(hb + 0);    /* k 0..31  (my type) */    \
    const short8 f1 = *(const short8*)(hb + 32);   /* k 32..63 */              \
    const floatx4 zf = {0.f, 0.f, 0.f, 0.f};                                   \
    /* one 4-deep chain per tile (all 4 split terms C-accumulated) */          \
    floatx4 d = __builtin_amdgcn_mfma_f32_16x16x32_bf16(whi[0][0], f0, zf, 0, 0, 0); \
    floatx4 e = __builtin_amdgcn_mfma_f32_16x16x32_bf16(whi[1][0], f0, zf, 0, 0, 0); \
    d = __builtin_amdgcn_mfma_f32_16x16x32_bf16(wlo[0][0], f0, d, 0, 0, 0);    \
    e = __builtin_amdgcn_mfma_f32_16x16x32_bf16(wlo[1][0], f0, e, 0, 0, 0);    \
    d = __builtin_amdgcn_mfma_f32_16x16x32_bf16(whi[0][1], f1, d, 0, 0, 0);    \
    e = __builtin_amdgcn_mfma_f32_16x16x32_bf16(whi[1][1], f1, e, 0, 0, 0);    \
    d = __builtin_amdgcn_mfma_f32_16x16x32_bf16(wlo[0][1], f1, d, 0, 0, 0);    \
    e = __builtin_amdgcn_mfma_f32_16x16x32_bf16(wlo[1][1], f1, e, 0, 0, 0);    \
    const float xt = xq[(TT)];                                                 \
    float p[4];                                                                \
    _Pragma("unroll") for (int j = 0; j < 4; ++j) {                            \
      const float pA = d[j] + swz8(d[j]);        /* tile 2wj:   hi+lo cols */  \
      const float pB = e[j] + swz8(e[j]);        /* tile 2wj+1: hi+lo cols */  \
      p[j] = (nhi ? pB : pA) + fmaf(xt, wih[j], bia[j]);                       \
    }                                                                          \
    const float ig = fsig(p[0]);                                               \
    const float fg = fsig(p[1]);                                               \
    const float gc = ftanh(p[2]);                                              \
    const float og = fsig(p[3]);                                               \
    c  = fmaf(fg, c, ig * gc);                                                 \
    hk = og * ftanh(c);                                                        \
    const ushort hib = (ushort)(__float_as_uint(hk) >> 16);  /* trunc split */ \
    ushort* hw = (HW) + woff;                                                  \
    hw[0]    = hib;                                                            \
    hw[LOFF] = f2bf(hk - bf2f(hib));     /* remainder exact, RN to bf16 */     \
    __syncthreads();                                                           \
  }

  for (int t = 0; t < T; t += 2) {
    STEP(hA, hB, t);
    STEP(hB, hA, t + 1);
  }
#undef STEP

  // ---- final h (fp32, from registers) -> LDS once; then the head ----
  hf[bat * FSTR + u] = hk;
  __syncthreads();
  if (tid < MB * 16) {
    const int bq = tid >> 4, j2 = tid & 15;   // 8 batches x 16 hidden2
    float s = fc1_b[j2];
    const float* fw = fc1_w + j2 * H;
#pragma unroll
    for (int k = 0; k < H; ++k) s = fmaf(hf[bq * FSTR + k], fw[k], s);
    s = fmaxf(s, 0.0f);
    zs[bq][j2] = s * fc2_w[j2];
  }
  __syncthreads();
  if (tid < MB) {
    float s = fc2_b[0];
#pragma unroll
    for (int j = 0; j < 16; ++j) s += zs[tid][j];
    out[b0 + tid] = s;
  }
}

}  // namespace

extern "C" void kernel_launch(void* const* d_in, const int* in_sizes, int n_in,
                              void* d_out, int out_size, void* d_ws, size_t ws_size,
                              hipStream_t stream) {
  const float* xg    = (const float*)d_in[0];
  const float* W_ih  = (const float*)d_in[1];
  const float* W_hh  = (const float*)d_in[2];
  const float* b_ih  = (const float*)d_in[3];
  const float* b_hh  = (const float*)d_in[4];
  const float* fc1_w = (const float*)d_in[5];
  const float* fc1_b = (const float*)d_in[6];
  const float* fc2_w = (const float*)d_in[7];
  const float* fc2_b = (const float*)d_in[8];
  float* out = (float*)d_out;

  dim3 grid(2048 / MB);   // 256 blocks -> 1 per CU, 8 waves = 2/SIMD
  dim3 block(TPB);
  hipLaunchKernelGGL(lstm_mfma, grid, block, 0, stream,
                     xg, W_ih, W_hh, b_ih, b_hh, fc1_w, fc1_b, fc2_w, fc2_b, out);
}